// Round 6
// baseline (141.643 us; speedup 1.0000x reference)
//
#include <hip/hip_runtime.h>

// ---------------------------------------------------------------------------
// maskselfattention: B=2, S=2048, D=1024, H=16, hd=64
// convert x,W to bf16 (W transposed) -> fused QKV GEMM (256x256 8-phase
// counted-vmcnt pipeline, bf16 MFMA, fp32 acc) writing Q,K [b][h][s][64] and
// V transposed [b][h][64][s] -> causal flash attention (4-wave blocks, paired
// q-tiles, LDS-staged K/V, fixed-reference-max softmax).
// ---------------------------------------------------------------------------

typedef unsigned short u16;
typedef __bf16 bf16x8 __attribute__((ext_vector_type(8)));
typedef float f32x4 __attribute__((ext_vector_type(4)));
typedef u16 u16x8 __attribute__((ext_vector_type(8)));

#define NB 2
#define NS 2048
#define ND 1024
#define NH 16
#define HD 64

__device__ __forceinline__ u16 f2bf(float f) {
    unsigned int u = __float_as_uint(f);
    unsigned int r = u + 0x7fffu + ((u >> 16) & 1u);
    return (u16)(r >> 16);
}

__device__ __forceinline__ f32x4 mfma16(bf16x8 a, bf16x8 b, f32x4 c) {
    return __builtin_amdgcn_mfma_f32_16x16x32_bf16(a, b, c, 0, 0, 0);
}

__device__ __forceinline__ void gl_lds16(const void* g, void* l) {
    __builtin_amdgcn_global_load_lds(
        (const __attribute__((address_space(1))) unsigned int*)g,
        (__attribute__((address_space(3))) unsigned int*)l, 16, 0, 0);
}

#define BAR()                              \
    do {                                   \
        __builtin_amdgcn_s_barrier();      \
        __builtin_amdgcn_sched_barrier(0); \
    } while (0)

// --- x (fp32) -> xb (bf16) -------------------------------------------------
__global__ __launch_bounds__(256) void convx_k(const float* __restrict__ x,
                                               u16* __restrict__ xb) {
    int i = (blockIdx.x * 256 + threadIdx.x) * 8;
    const float4* p = (const float4*)(x + i);
    float4 a = p[0], c = p[1];
    u16x8 r;
    r[0] = f2bf(a.x); r[1] = f2bf(a.y); r[2] = f2bf(a.z); r[3] = f2bf(a.w);
    r[4] = f2bf(c.x); r[5] = f2bf(c.y); r[6] = f2bf(c.z); r[7] = f2bf(c.w);
    *(u16x8*)(xb + i) = r;
}

// --- W [k][n] fp32 -> Wt [z][n][k] bf16 ------------------------------------
__global__ __launch_bounds__(256) void convw_k(const float* __restrict__ wq,
                                               const float* __restrict__ wk,
                                               const float* __restrict__ wv,
                                               u16* __restrict__ wt) {
    __shared__ float tile[32][33];
    const int z = blockIdx.z;
    const float* W = (z == 0) ? wq : (z == 1) ? wk : wv;
    const int k0 = blockIdx.x * 32, n0 = blockIdx.y * 32;
    const int tx = threadIdx.x & 31, ty = threadIdx.x >> 5;
#pragma unroll
    for (int rr = 0; rr < 32; rr += 8)
        tile[ty + rr][tx] = W[(size_t)(k0 + ty + rr) * ND + n0 + tx];
    __syncthreads();
    u16* dst = wt + (size_t)z * ND * ND;
#pragma unroll
    for (int rr = 0; rr < 32; rr += 8)
        dst[(size_t)(n0 + ty + rr) * ND + k0 + tx] = f2bf(tile[tx][ty + rr]);
}

// --- 256x256 8-phase fused QKV GEMM ----------------------------------------
// 512 threads = 8 waves (2M x 4N), wave owns 128x64 output. BK=64, 16 K-tiles,
// 2 tiles per iteration (bufs 0/1), 8 phases/iter, counted vmcnt(2)/(4) at
// P4/P8 only. LDS XOR-swizzle byte^=((row&7)<<4): inverse applied to global
// source (gl_lds writes linearly), same applied on ds_read.
// NOTE: __launch_bounds__(512, 1): 128 KiB LDS already caps at 1 block/CU;
// a tighter bound caused a 128-VGPR cap -> acc[8][4] spilled (~110 MB scratch
// writes observed in r5). 1 wave/EU min -> 256 VGPR budget, no spill.

__device__ __forceinline__ void stage_half(const u16* __restrict__ g,
                                           int grow0, int kt, u16* ldsr,
                                           int t) {
#pragma unroll
    for (int c = 0; c < 2; c++) {
        const int P = c * 8192 + t * 16;  // byte offset in half-tile
        const int R = P >> 7;             // row 0..127
        const int colb = (P & 127) ^ ((R & 7) << 4);
        gl_lds16((const char*)g + (size_t)(grow0 + R) * 2048 + kt * 128 + colb,
                 (char*)ldsr + P);
    }
}

__device__ __forceinline__ bf16x8 lfrag(const u16* base, int row, int colb) {
    return *(const bf16x8*)((const char*)base + row * 128 +
                            (colb ^ ((row & 7) << 4)));
}

__device__ __forceinline__ void load_fb(const u16* bs, int wc, int fr, int ks,
                                        bf16x8 fb[4][2]) {
#pragma unroll
    for (int nf = 0; nf < 4; nf++)
#pragma unroll
        for (int c = 0; c < 2; c++)
            fb[nf][c] = lfrag(bs, wc * 64 + nf * 16 + fr, c * 64 + ks * 16);
}

__device__ __forceinline__ void load_fa(const u16* as, int q, int wr, int fr,
                                        int ks, bf16x8 fa[2][2]) {
#pragma unroll
    for (int m2 = 0; m2 < 2; m2++)
#pragma unroll
        for (int c = 0; c < 2; c++)
            fa[m2][c] =
                lfrag(as, wr * 128 + (q * 2 + m2) * 16 + fr, c * 64 + ks * 16);
}

__device__ __forceinline__ void cluster(int q, int z, const bf16x8 fa[2][2],
                                        const bf16x8 fb[4][2],
                                        f32x4 acc[8][4]) {
    __builtin_amdgcn_s_setprio(1);
    if (z == 2) {
#pragma unroll
        for (int m2 = 0; m2 < 2; m2++)
#pragma unroll
            for (int nf = 0; nf < 4; nf++)
#pragma unroll
                for (int c = 0; c < 2; c++)
                    acc[q * 2 + m2][nf] =
                        mfma16(fb[nf][c], fa[m2][c], acc[q * 2 + m2][nf]);
    } else {
#pragma unroll
        for (int m2 = 0; m2 < 2; m2++)
#pragma unroll
            for (int nf = 0; nf < 4; nf++)
#pragma unroll
                for (int c = 0; c < 2; c++)
                    acc[q * 2 + m2][nf] =
                        mfma16(fa[m2][c], fb[nf][c], acc[q * 2 + m2][nf]);
    }
    __builtin_amdgcn_s_setprio(0);
}

__global__ __launch_bounds__(512, 1) void qkv256_k(const u16* __restrict__ xb,
                                                   const u16* __restrict__ wt,
                                                   u16* __restrict__ qh,
                                                   u16* __restrict__ kh,
                                                   u16* __restrict__ vt) {
    extern __shared__ u16 smem[];  // 128 KiB
    u16* As0 = smem;               // [2][16384]
    u16* As1 = smem + 16384;
    u16* Bs0 = smem + 32768;
    u16* Bs1 = smem + 49152;

    const int z = blockIdx.z;
    const int m0 = blockIdx.x * 256;
    const int n0 = blockIdx.y * 256;
    const u16* gA = xb;                        // rows m, 1024 elems
    const u16* gB = wt + (size_t)z * ND * ND;  // rows n, 1024 elems
    const int t = threadIdx.x;
    const int lane = t & 63;
    const int w = t >> 6;
    const int wr = w >> 2, wc = w & 3;
    const int fr = lane & 15, ks = lane >> 4;

    f32x4 acc[8][4] = {};

#define STA(BUF, HH, KT) stage_half(gA, m0 + (HH)*128, (KT), (BUF) + (HH)*8192, t)
#define STB(BUF, HH, KT) stage_half(gB, n0 + (HH)*128, (KT), (BUF) + (HH)*8192, t)

    // prologue: B(0)->buf0, A(0)->buf0, B(1)->buf1; keep B(1) in flight
    STB(Bs0, 0, 0); STB(Bs0, 1, 0);
    STA(As0, 0, 0); STA(As0, 1, 0);
    STB(Bs1, 0, 1); STB(Bs1, 1, 1);
    asm volatile("s_waitcnt vmcnt(4)" ::: "memory");
    BAR();

    const int NI = 8;  // K / 128
    for (int j = 0; j < NI; ++j) {
        const int g = (j + 1 < NI);
        const int t1 = 2 * j + 1;
        bf16x8 fb[4][2];
        {  // P1: q0 of tile t0 (buf0); stage A-lo(t1)->buf1
            bf16x8 fa[2][2];
            load_fb(Bs0, wc, fr, ks, fb);
            load_fa(As0, 0, wr, fr, ks, fa);
            STA(As1, 0, t1);
            BAR();
            cluster(0, z, fa, fb, acc);
            BAR();
        }
        {  // P2: stage A-hi(t1)->buf1, B-lo(t0+2)->buf0
            bf16x8 fa[2][2];
            load_fa(As0, 1, wr, fr, ks, fa);
            STA(As1, 1, t1);
            if (g) STB(Bs0, 0, t1 + 1);
            BAR();
            cluster(1, z, fa, fb, acc);
            BAR();
        }
        {  // P3: stage B-hi(t0+2)->buf0
            bf16x8 fa[2][2];
            load_fa(As0, 2, wr, fr, ks, fa);
            if (g) STB(Bs0, 1, t1 + 1);
            BAR();
            cluster(2, z, fa, fb, acc);
            BAR();
        }
        {  // P4: gate (A(t1), B(t1) must be landed for P5)
            bf16x8 fa[2][2];
            load_fa(As0, 3, wr, fr, ks, fa);
            if (j == NI - 1) {
                asm volatile("s_waitcnt vmcnt(0)" ::: "memory");
            } else {
                asm volatile("s_waitcnt vmcnt(2)" ::: "memory");
            }
            BAR();
            cluster(3, z, fa, fb, acc);
            BAR();
        }
        {  // P5: q0 of tile t1 (buf1); stage A-lo(t0+2)->buf0
            bf16x8 fa[2][2];
            load_fb(Bs1, wc, fr, ks, fb);
            load_fa(As1, 0, wr, fr, ks, fa);
            if (g) STA(As0, 0, t1 + 1);
            BAR();
            cluster(0, z, fa, fb, acc);
            BAR();
        }
        {  // P6: stage A-hi(t0+2)->buf0
            bf16x8 fa[2][2];
            load_fa(As1, 1, wr, fr, ks, fa);
            if (g) STA(As0, 1, t1 + 1);
            BAR();
            cluster(1, z, fa, fb, acc);
            BAR();
        }
        {  // P7: stage B-lo(t1+2)->buf1
            bf16x8 fa[2][2];
            load_fa(As1, 2, wr, fr, ks, fa);
            if (g) STB(Bs1, 0, t1 + 2);
            BAR();
            cluster(2, z, fa, fb, acc);
            BAR();
        }
        {  // P8: stage B-hi(t1+2)->buf1; gate vmcnt(4)
            bf16x8 fa[2][2];
            load_fa(As1, 3, wr, fr, ks, fa);
            if (g) STB(Bs1, 1, t1 + 2);
            asm volatile("s_waitcnt vmcnt(4)" ::: "memory");
            BAR();
            cluster(3, z, fa, fb, acc);
            BAR();
        }
    }
#undef STA
#undef STB

    if (z < 2) {
        u16* dst = (z == 0) ? qh : kh;
#pragma unroll
        for (int mf = 0; mf < 8; mf++)
#pragma unroll
            for (int nf = 0; nf < 4; nf++)
#pragma unroll
                for (int r = 0; r < 4; r++) {
                    const int mg = m0 + wr * 128 + mf * 16 + ks * 4 + r;
                    const int ng = n0 + wc * 64 + nf * 16 + fr;
                    const int b = mg >> 11, s = mg & 2047;
                    const int hh = ng >> 6, dd = ng & 63;
                    dst[(((size_t)b * NH + hh) * NS + s) * HD + dd] =
                        f2bf(acc[mf][nf][r]);
                }
    } else {
#pragma unroll
        for (int mf = 0; mf < 8; mf++)
#pragma unroll
            for (int nf = 0; nf < 4; nf++)
#pragma unroll
                for (int r = 0; r < 4; r++) {
                    const int ng = n0 + wc * 64 + nf * 16 + ks * 4 + r;
                    const int mg = m0 + wr * 128 + mf * 16 + fr;
                    const int b = mg >> 11, s = mg & 2047;
                    const int hh = ng >> 6, dd = ng & 63;
                    vt[(((size_t)b * NH + hh) * HD + dd) * NS + s] =
                        f2bf(acc[mf][nf][r]);
                }
    }
}

// --- causal flash attention ------------------------------------------------
// 512 blocks x 256 threads (4 waves). bh = blk&31 (XCD-affine), p = blk>>5.
// Block handles q-tiles A=31-p (heavy) and B=p (light): uniform 33 KV-iters.
// K/V 64-row tiles staged in LDS (double-buffered, swizzled). Chains share
// staged tiles + fragments. Fixed-reference-max softmax p=exp(s/8-8);
// row-sum via all-ones MFMA accumulator.

__device__ __forceinline__ void stage_kv(const u16* __restrict__ K,
                                         const u16* __restrict__ V, int kv0,
                                         u16* Kl, u16* Vl, int t) {
#pragma unroll
    for (int c = 0; c < 2; c++) {
        const int L = c * 4096 + t * 16;
        const int row = L >> 7;
        const int cb = (L & 127) ^ ((row & 7) << 4);
        gl_lds16((const char*)K + (size_t)(kv0 + row) * 128 + cb,
                 (char*)Kl + L);
        gl_lds16((const char*)V + (size_t)row * (NS * 2) + kv0 * 2 + cb,
                 (char*)Vl + L);
    }
}

template <bool MASKED>
__device__ __forceinline__ void sm_px(const f32x4* sc, u16* pl, int kv0,
                                      int q0, int fr, int ks) {
#pragma unroll
    for (int r = 0; r < 4; r++) {
        const int row = ks * 4 + r;
        const int qg = q0 + row;
#pragma unroll
        for (int kf = 0; kf < 4; kf++) {
            float s = sc[kf][r];
            if (MASKED && (kv0 + kf * 16 + fr > qg)) s = -3.0e38f;
            float pp = __expf(fmaf(s, 0.125f, -8.0f));
            const int k = kf * 16 + fr;
            const int c = (k >> 3) ^ (row & 7);
            *(u16*)((char*)pl + row * 128 + (c << 4) + ((k & 7) << 1)) =
                f2bf(pp);
        }
    }
}

__device__ __forceinline__ void pv_lds(const bf16x8 (*fv)[2], const u16* pl,
                                       f32x4* o, f32x4& lacc, bf16x8 ones,
                                       int fr, int ks) {
    bf16x8 pa[2];
#pragma unroll
    for (int s2 = 0; s2 < 2; s2++) {
        const int c = (s2 * 4 + ks) ^ (fr & 7);
        pa[s2] = *(const bf16x8*)((const char*)pl + fr * 128 + (c << 4));
    }
    lacc = mfma16(pa[0], ones, lacc);
    lacc = mfma16(pa[1], ones, lacc);
#pragma unroll
    for (int j = 0; j < 4; j++)
#pragma unroll
        for (int s2 = 0; s2 < 2; s2++) o[j] = mfma16(pa[s2], fv[j][s2], o[j]);
}

__global__ __launch_bounds__(256, 2) void attn_k(const u16* __restrict__ qh,
                                                 const u16* __restrict__ kh,
                                                 const u16* __restrict__ vt,
                                                 float* __restrict__ out) {
    const int t = threadIdx.x, lane = t & 63, wv = t >> 6;
    const int fr = lane & 15, ks = lane >> 4;
    const int bh = blockIdx.x & 31;
    const int p = blockIdx.x >> 5;  // 0..15
    const int b = bh >> 4, h = bh & 15;
    const int tileA = 31 - p, tileB = p;
    const int qA = tileA * 64 + wv * 16;
    const int qB = tileB * 64 + wv * 16;
    const int nA = tileA + 1, nB = tileB + 1;
    const u16* Q = qh + (size_t)bh * NS * HD;
    const u16* K = kh + (size_t)bh * NS * HD;
    const u16* V = vt + (size_t)bh * HD * NS;

    __shared__ u16 Kl[2][64 * 64];
    __shared__ u16 Vl[2][64 * 64];
    __shared__ u16 P[4][2][16 * 64];
    u16* plA = &P[wv][0][0];
    u16* plB = &P[wv][1][0];

    bf16x8 fqA[2], fqB[2];
#pragma unroll
    for (int sl = 0; sl < 2; sl++) {
        fqA[sl] = *(const bf16x8*)&Q[(qA + fr) * HD + sl * 32 + ks * 8];
        fqB[sl] = *(const bf16x8*)&Q[(qB + fr) * HD + sl * 32 + ks * 8];
    }

    u16x8 ob;
#pragma unroll
    for (int j = 0; j < 8; j++) ob[j] = 0x3F80;  // bf16 1.0
    const bf16x8 ones = __builtin_bit_cast(bf16x8, ob);

    f32x4 oA[4] = {}, oB[4] = {};
    f32x4 lA = {}, lB = {};

    stage_kv(K, V, 0, &Kl[0][0], &Vl[0][0], t);
    __syncthreads();

    for (int it = 0; it < nA; ++it) {
        const int cur = it & 1;
        const int kv0 = it * 64;
        if (it + 1 < nA)
            stage_kv(K, V, kv0 + 64, &Kl[cur ^ 1][0], &Vl[cur ^ 1][0], t);

        bf16x8 fk[4][2];
#pragma unroll
        for (int kf = 0; kf < 4; kf++)
#pragma unroll
            for (int sl = 0; sl < 2; sl++)
                fk[kf][sl] = *(const bf16x8*)((const char*)&Kl[cur][0] +
                                              (kf * 16 + fr) * 128 +
                                              ((sl * 64 + ks * 16) ^
                                               ((fr & 7) << 4)));

        f32x4 scA[4] = {};
#pragma unroll
        for (int kf = 0; kf < 4; kf++) {
            scA[kf] = mfma16(fqA[0], fk[kf][0], scA[kf]);
            scA[kf] = mfma16(fqA[1], fk[kf][1], scA[kf]);
        }
        const bool doB = it < nB;
        f32x4 scB[4] = {};
        if (doB) {
#pragma unroll
            for (int kf = 0; kf < 4; kf++) {
                scB[kf] = mfma16(fqB[0], fk[kf][0], scB[kf]);
                scB[kf] = mfma16(fqB[1], fk[kf][1], scB[kf]);
            }
        }

        if (it == nA - 1)
            sm_px<true>(scA, plA, kv0, qA, fr, ks);
        else
            sm_px<false>(scA, plA, kv0, qA, fr, ks);
        if (doB) {
            if (it == nB - 1)
                sm_px<true>(scB, plB, kv0, qB, fr, ks);
            else
                sm_px<false>(scB, plB, kv0, qB, fr, ks);
        }

        bf16x8 fv[4][2];
#pragma unroll
        for (int j = 0; j < 4; j++)
#pragma unroll
            for (int s2 = 0; s2 < 2; s2++)
                fv[j][s2] = *(const bf16x8*)((const char*)&Vl[cur][0] +
                                             (j * 16 + fr) * 128 +
                                             ((s2 * 64 + ks * 16) ^
                                              ((fr & 7) << 4)));

        pv_lds(fv, plA, oA, lA, ones, fr, ks);
        if (doB) pv_lds(fv, plB, oB, lB, ones, fr, ks);

        __syncthreads();
    }

    float rlA[4], rlB[4];
#pragma unroll
    for (int r = 0; r < 4; r++) {
        rlA[r] = 1.0f / lA[r];
        rlB[r] = 1.0f / lB[r];
    }
#pragma unroll
    for (int j = 0; j < 4; j++)
#pragma unroll
        for (int r = 0; r < 4; r++) {
            const int qgA = qA + ks * 4 + r;
            const int qgB = qB + ks * 4 + r;
            out[((size_t)b * NS + qgA) * ND + h * HD + j * 16 + fr] =
                oA[j][r] * rlA[r];
            out[((size_t)b * NS + qgB) * ND + h * HD + j * 16 + fr] =
                oB[j][r] * rlB[r];
        }
}

extern "C" void kernel_launch(void* const* d_in, const int* in_sizes, int n_in,
                              void* d_out, int out_size, void* d_ws,
                              size_t ws_size, hipStream_t stream) {
    const float* x = (const float*)d_in[0];
    const float* wq = (const float*)d_in[1];
    const float* wk = (const float*)d_in[2];
    const float* wvp = (const float*)d_in[3];
    float* out = (float*)d_out;

    char* w8 = (char*)d_ws;
    u16* xb = (u16*)(w8);                      // 8 MiB
    u16* wt = (u16*)(w8 + ((size_t)8 << 20));  // 6 MiB
    u16* qh = (u16*)(w8 + ((size_t)14 << 20));
    u16* kh = (u16*)(w8 + ((size_t)22 << 20));
    u16* vt = (u16*)(w8 + ((size_t)30 << 20));

    convx_k<<<(NB * NS * ND) / (256 * 8), 256, 0, stream>>>(x, xb);
    convw_k<<<dim3(ND / 32, ND / 32, 3), 256, 0, stream>>>(wq, wk, wvp, wt);
    qkv256_k<<<dim3((NB * NS) / 256, ND / 256, 3), 512, 131072, stream>>>(
        xb, wt, qh, kh, vt);
    attn_k<<<512, 256, 0, stream>>>(qh, kh, vt, out);
}

// Round 7
// 112.246 us; speedup vs baseline: 1.2619x; 1.2619x over previous
//
#include <hip/hip_runtime.h>

// ---------------------------------------------------------------------------
// maskselfattention: B=2, S=2048, D=1024, H=16, hd=64
// convert x,W to bf16 (W transposed) -> fused QKV GEMM (128x128 tile, BK=64,
// XOR-swizzled LDS, bf16 MFMA, fp32 acc) writing Q,K [b][h][s][64] and V
// transposed [b][h][64][s] -> causal flash attention (4-wave blocks, paired
// q-tiles, LDS-staged K/V, fixed-reference-max softmax).
// ---------------------------------------------------------------------------

typedef unsigned short u16;
typedef __bf16 bf16x8 __attribute__((ext_vector_type(8)));
typedef float f32x4 __attribute__((ext_vector_type(4)));
typedef u16 u16x8 __attribute__((ext_vector_type(8)));

#define NB 2
#define NS 2048
#define ND 1024
#define NH 16
#define HD 64

__device__ __forceinline__ u16 f2bf(float f) {
    unsigned int u = __float_as_uint(f);
    unsigned int r = u + 0x7fffu + ((u >> 16) & 1u);
    return (u16)(r >> 16);
}

__device__ __forceinline__ f32x4 mfma16(bf16x8 a, bf16x8 b, f32x4 c) {
    return __builtin_amdgcn_mfma_f32_16x16x32_bf16(a, b, c, 0, 0, 0);
}

__device__ __forceinline__ void gl_lds16(const void* g, void* l) {
    __builtin_amdgcn_global_load_lds(
        (const __attribute__((address_space(1))) unsigned int*)g,
        (__attribute__((address_space(3))) unsigned int*)l, 16, 0, 0);
}

// swizzled LDS fragment read from a [rows][128B] tile
__device__ __forceinline__ bf16x8 ldsw(const u16* base, int row, int colb) {
    return *(const bf16x8*)((const char*)base + row * 128 +
                            (colb ^ ((row & 7) << 4)));
}

// --- x (fp32) -> xb (bf16) -------------------------------------------------
__global__ __launch_bounds__(256) void convx_k(const float* __restrict__ x,
                                               u16* __restrict__ xb) {
    int i = (blockIdx.x * 256 + threadIdx.x) * 8;
    const float4* p = (const float4*)(x + i);
    float4 a = p[0], c = p[1];
    u16x8 r;
    r[0] = f2bf(a.x); r[1] = f2bf(a.y); r[2] = f2bf(a.z); r[3] = f2bf(a.w);
    r[4] = f2bf(c.x); r[5] = f2bf(c.y); r[6] = f2bf(c.z); r[7] = f2bf(c.w);
    *(u16x8*)(xb + i) = r;
}

// --- W [k][n] fp32 -> Wt [z][n][k] bf16 ------------------------------------
__global__ __launch_bounds__(256) void convw_k(const float* __restrict__ wq,
                                               const float* __restrict__ wk,
                                               const float* __restrict__ wv,
                                               u16* __restrict__ wt) {
    __shared__ float tile[32][33];
    const int z = blockIdx.z;
    const float* W = (z == 0) ? wq : (z == 1) ? wk : wv;
    const int k0 = blockIdx.x * 32, n0 = blockIdx.y * 32;
    const int tx = threadIdx.x & 31, ty = threadIdx.x >> 5;
#pragma unroll
    for (int rr = 0; rr < 32; rr += 8)
        tile[ty + rr][tx] = W[(size_t)(k0 + ty + rr) * ND + n0 + tx];
    __syncthreads();
    u16* dst = wt + (size_t)z * ND * ND;
#pragma unroll
    for (int rr = 0; rr < 32; rr += 8)
        dst[(size_t)(n0 + ty + rr) * ND + k0 + tx] = f2bf(tile[tx][ty + rr]);
}

// --- fused QKV GEMM --------------------------------------------------------
// 128x128 tile, BK=64 (128B LDS rows), 256 threads (4 waves, each 64x64).
// LDS XOR-swizzle byte^=((row&7)<<4): inverse pre-applied to the global
// source of global_load_lds (linear LDS dest), same XOR applied on
// ds_read_b128 -> conflict-free fragment reads (2-way per 16-lane group).
// z<2: C=xb@W written [b][h][s][64]; z==2: C^T via swapped mfma operands,
// written as Vt [b][h][64][s].
__global__ __launch_bounds__(256) void qkv_gemm_k(const u16* __restrict__ xb,
                                                  const u16* __restrict__ wt,
                                                  u16* __restrict__ qh,
                                                  u16* __restrict__ kh,
                                                  u16* __restrict__ vt) {
    __shared__ u16 At[128 * 64];  // 16 KiB, rows of 128B (swizzled)
    __shared__ u16 Bt[128 * 64];
    const int z = blockIdx.z;
    const int m0 = blockIdx.x * 128;
    const int n0 = blockIdx.y * 128;
    const u16* w = wt + (size_t)z * ND * ND;
    const int t = threadIdx.x;
    const int lane = t & 63;
    const int wv = t >> 6;
    const int wm = (wv >> 1) * 64, wn = (wv & 1) * 64;
    const int fr = lane & 15;
    const int ks = lane >> 4;

    f32x4 acc[4][4] = {};

    for (int kt = 0; kt < ND; kt += 64) {
        // stage A and B tiles: 4 x 16B per thread each, linear LDS dest,
        // inverse-swizzled global source
#pragma unroll
        for (int c = 0; c < 4; c++) {
            const int L = c * 4096 + t * 16;  // byte offset in tile
            const int row = L >> 7;
            const int cb = (L & 127) ^ ((row & 7) << 4);
            gl_lds16((const char*)xb + (size_t)(m0 + row) * 2048 + kt * 2 + cb,
                     (char*)At + L);
            gl_lds16((const char*)w + (size_t)(n0 + row) * 2048 + kt * 2 + cb,
                     (char*)Bt + L);
        }
        __syncthreads();

        bf16x8 fa[4][2], fb[4][2];
#pragma unroll
        for (int i = 0; i < 4; i++)
#pragma unroll
            for (int c = 0; c < 2; c++) {
                fa[i][c] = ldsw(At, wm + i * 16 + fr, c * 64 + ks * 16);
                fb[i][c] = ldsw(Bt, wn + i * 16 + fr, c * 64 + ks * 16);
            }

        if (z < 2) {
#pragma unroll
            for (int i = 0; i < 4; i++)
#pragma unroll
                for (int j = 0; j < 4; j++)
#pragma unroll
                    for (int c = 0; c < 2; c++)
                        acc[i][j] = mfma16(fa[i][c], fb[j][c], acc[i][j]);
        } else {
#pragma unroll
            for (int i = 0; i < 4; i++)
#pragma unroll
                for (int j = 0; j < 4; j++)
#pragma unroll
                    for (int c = 0; c < 2; c++)
                        acc[i][j] = mfma16(fb[j][c], fa[i][c], acc[i][j]);
        }
        __syncthreads();
    }

    if (z < 2) {
        u16* dst = (z == 0) ? qh : kh;
#pragma unroll
        for (int i = 0; i < 4; i++)
#pragma unroll
            for (int j = 0; j < 4; j++)
#pragma unroll
                for (int r = 0; r < 4; r++) {
                    int mg = m0 + wm + i * 16 + ks * 4 + r;
                    int ng = n0 + wn + j * 16 + fr;
                    int b = mg >> 11, s = mg & 2047;
                    int hh = ng >> 6, dd = ng & 63;
                    dst[(((size_t)b * NH + hh) * NS + s) * HD + dd] =
                        f2bf(acc[i][j][r]);
                }
    } else {
#pragma unroll
        for (int i = 0; i < 4; i++)
#pragma unroll
            for (int j = 0; j < 4; j++)
#pragma unroll
                for (int r = 0; r < 4; r++) {
                    int ng = n0 + wn + j * 16 + ks * 4 + r;  // d-dim
                    int mg = m0 + wm + i * 16 + fr;          // s-dim
                    int b = mg >> 11, s = mg & 2047;
                    int hh = ng >> 6, dd = ng & 63;
                    vt[(((size_t)b * NH + hh) * HD + dd) * NS + s] =
                        f2bf(acc[i][j][r]);
                }
    }
}

// --- causal flash attention ------------------------------------------------
// 512 blocks x 256 threads (4 waves). bh = blk&31 (XCD-affine), p = blk>>5.
// Block handles q-tiles A=31-p (heavy) and B=p (light): uniform 33 KV-iters.
// K/V 64-row tiles staged in LDS (double-buffered, swizzled). Chains share
// staged tiles + fragments. Fixed-reference-max softmax p=exp(s/8-8);
// row-sum via all-ones MFMA accumulator.

__device__ __forceinline__ void stage_kv(const u16* __restrict__ K,
                                         const u16* __restrict__ V, int kv0,
                                         u16* Kl, u16* Vl, int t) {
#pragma unroll
    for (int c = 0; c < 2; c++) {
        const int L = c * 4096 + t * 16;
        const int row = L >> 7;
        const int cb = (L & 127) ^ ((row & 7) << 4);
        gl_lds16((const char*)K + (size_t)(kv0 + row) * 128 + cb,
                 (char*)Kl + L);
        gl_lds16((const char*)V + (size_t)row * (NS * 2) + kv0 * 2 + cb,
                 (char*)Vl + L);
    }
}

template <bool MASKED>
__device__ __forceinline__ void sm_px(const f32x4* sc, u16* pl, int kv0,
                                      int q0, int fr, int ks) {
#pragma unroll
    for (int r = 0; r < 4; r++) {
        const int row = ks * 4 + r;
        const int qg = q0 + row;
#pragma unroll
        for (int kf = 0; kf < 4; kf++) {
            float s = sc[kf][r];
            if (MASKED && (kv0 + kf * 16 + fr > qg)) s = -3.0e38f;
            float pp = __expf(fmaf(s, 0.125f, -8.0f));
            const int k = kf * 16 + fr;
            const int c = (k >> 3) ^ (row & 7);
            *(u16*)((char*)pl + row * 128 + (c << 4) + ((k & 7) << 1)) =
                f2bf(pp);
        }
    }
}

__device__ __forceinline__ void pv_lds(const bf16x8 (*fv)[2], const u16* pl,
                                       f32x4* o, f32x4& lacc, bf16x8 ones,
                                       int fr, int ks) {
    bf16x8 pa[2];
#pragma unroll
    for (int s2 = 0; s2 < 2; s2++) {
        const int c = (s2 * 4 + ks) ^ (fr & 7);
        pa[s2] = *(const bf16x8*)((const char*)pl + fr * 128 + (c << 4));
    }
    lacc = mfma16(pa[0], ones, lacc);
    lacc = mfma16(pa[1], ones, lacc);
#pragma unroll
    for (int j = 0; j < 4; j++)
#pragma unroll
        for (int s2 = 0; s2 < 2; s2++) o[j] = mfma16(pa[s2], fv[j][s2], o[j]);
}

__global__ __launch_bounds__(256, 2) void attn_k(const u16* __restrict__ qh,
                                                 const u16* __restrict__ kh,
                                                 const u16* __restrict__ vt,
                                                 float* __restrict__ out) {
    const int t = threadIdx.x, lane = t & 63, wv = t >> 6;
    const int fr = lane & 15, ks = lane >> 4;
    const int bh = blockIdx.x & 31;
    const int p = blockIdx.x >> 5;  // 0..15
    const int b = bh >> 4, h = bh & 15;
    const int tileA = 31 - p, tileB = p;
    const int qA = tileA * 64 + wv * 16;
    const int qB = tileB * 64 + wv * 16;
    const int nA = tileA + 1, nB = tileB + 1;
    const u16* Q = qh + (size_t)bh * NS * HD;
    const u16* K = kh + (size_t)bh * NS * HD;
    const u16* V = vt + (size_t)bh * HD * NS;

    __shared__ u16 Kl[2][64 * 64];
    __shared__ u16 Vl[2][64 * 64];
    __shared__ u16 P[4][2][16 * 64];
    u16* plA = &P[wv][0][0];
    u16* plB = &P[wv][1][0];

    bf16x8 fqA[2], fqB[2];
#pragma unroll
    for (int sl = 0; sl < 2; sl++) {
        fqA[sl] = *(const bf16x8*)&Q[(qA + fr) * HD + sl * 32 + ks * 8];
        fqB[sl] = *(const bf16x8*)&Q[(qB + fr) * HD + sl * 32 + ks * 8];
    }

    u16x8 ob;
#pragma unroll
    for (int j = 0; j < 8; j++) ob[j] = 0x3F80;  // bf16 1.0
    const bf16x8 ones = __builtin_bit_cast(bf16x8, ob);

    f32x4 oA[4] = {}, oB[4] = {};
    f32x4 lA = {}, lB = {};

    stage_kv(K, V, 0, &Kl[0][0], &Vl[0][0], t);
    __syncthreads();

    for (int it = 0; it < nA; ++it) {
        const int cur = it & 1;
        const int kv0 = it * 64;
        if (it + 1 < nA)
            stage_kv(K, V, kv0 + 64, &Kl[cur ^ 1][0], &Vl[cur ^ 1][0], t);

        bf16x8 fk[4][2];
#pragma unroll
        for (int kf = 0; kf < 4; kf++)
#pragma unroll
            for (int sl = 0; sl < 2; sl++)
                fk[kf][sl] = *(const bf16x8*)((const char*)&Kl[cur][0] +
                                              (kf * 16 + fr) * 128 +
                                              ((sl * 64 + ks * 16) ^
                                               ((fr & 7) << 4)));

        f32x4 scA[4] = {};
#pragma unroll
        for (int kf = 0; kf < 4; kf++) {
            scA[kf] = mfma16(fqA[0], fk[kf][0], scA[kf]);
            scA[kf] = mfma16(fqA[1], fk[kf][1], scA[kf]);
        }
        const bool doB = it < nB;
        f32x4 scB[4] = {};
        if (doB) {
#pragma unroll
            for (int kf = 0; kf < 4; kf++) {
                scB[kf] = mfma16(fqB[0], fk[kf][0], scB[kf]);
                scB[kf] = mfma16(fqB[1], fk[kf][1], scB[kf]);
            }
        }

        if (it == nA - 1)
            sm_px<true>(scA, plA, kv0, qA, fr, ks);
        else
            sm_px<false>(scA, plA, kv0, qA, fr, ks);
        if (doB) {
            if (it == nB - 1)
                sm_px<true>(scB, plB, kv0, qB, fr, ks);
            else
                sm_px<false>(scB, plB, kv0, qB, fr, ks);
        }

        bf16x8 fv[4][2];
#pragma unroll
        for (int j = 0; j < 4; j++)
#pragma unroll
            for (int s2 = 0; s2 < 2; s2++)
                fv[j][s2] = *(const bf16x8*)((const char*)&Vl[cur][0] +
                                             (j * 16 + fr) * 128 +
                                             ((s2 * 64 + ks * 16) ^
                                              ((fr & 7) << 4)));

        pv_lds(fv, plA, oA, lA, ones, fr, ks);
        if (doB) pv_lds(fv, plB, oB, lB, ones, fr, ks);

        __syncthreads();
    }

    float rlA[4], rlB[4];
#pragma unroll
    for (int r = 0; r < 4; r++) {
        rlA[r] = 1.0f / lA[r];
        rlB[r] = 1.0f / lB[r];
    }
#pragma unroll
    for (int j = 0; j < 4; j++)
#pragma unroll
        for (int r = 0; r < 4; r++) {
            const int qgA = qA + ks * 4 + r;
            const int qgB = qB + ks * 4 + r;
            out[((size_t)b * NS + qgA) * ND + h * HD + j * 16 + fr] =
                oA[j][r] * rlA[r];
            out[((size_t)b * NS + qgB) * ND + h * HD + j * 16 + fr] =
                oB[j][r] * rlB[r];
        }
}

extern "C" void kernel_launch(void* const* d_in, const int* in_sizes, int n_in,
                              void* d_out, int out_size, void* d_ws,
                              size_t ws_size, hipStream_t stream) {
    const float* x = (const float*)d_in[0];
    const float* wq = (const float*)d_in[1];
    const float* wk = (const float*)d_in[2];
    const float* wvp = (const float*)d_in[3];
    float* out = (float*)d_out;

    char* w8 = (char*)d_ws;
    u16* xb = (u16*)(w8);                      // 8 MiB
    u16* wt = (u16*)(w8 + ((size_t)8 << 20));  // 6 MiB
    u16* qh = (u16*)(w8 + ((size_t)14 << 20));
    u16* kh = (u16*)(w8 + ((size_t)22 << 20));
    u16* vt = (u16*)(w8 + ((size_t)30 << 20));

    convx_k<<<(NB * NS * ND) / (256 * 8), 256, 0, stream>>>(x, xb);
    convw_k<<<dim3(ND / 32, ND / 32, 3), 256, 0, stream>>>(wq, wk, wvp, wt);
    qkv_gemm_k<<<dim3((NB * NS) / 128, ND / 128, 3), 256, 0, stream>>>(
        xb, wt, qh, kh, vt);
    attn_k<<<512, 256, 0, stream>>>(qh, kh, vt, out);
}

// Round 8
// 82.878 us; speedup vs baseline: 1.7091x; 1.3543x over previous
//
#include <hip/hip_runtime.h>

// ---------------------------------------------------------------------------
// maskselfattention: B=2, S=2048, D=1024, H=16, hd=64
// convert x,W to bf16 (W transposed) -> ONE fused QKV GEMM (z-fused: A tile
// staged once, 3 B tiles, 3x MFMA per barrier; 128x64 tile, BK=64, swizzled
// LDS) writing Q,K [b][h][s][64] and V transposed [b][h][64][s] -> causal
// flash attention (4-wave blocks, paired q-tiles, LDS-staged K/V,
// fixed-reference-max softmax).
// ---------------------------------------------------------------------------

typedef unsigned short u16;
typedef __bf16 bf16x8 __attribute__((ext_vector_type(8)));
typedef float f32x4 __attribute__((ext_vector_type(4)));
typedef u16 u16x8 __attribute__((ext_vector_type(8)));

#define NB 2
#define NS 2048
#define ND 1024
#define NH 16
#define HD 64

__device__ __forceinline__ u16 f2bf(float f) {
    unsigned int u = __float_as_uint(f);
    unsigned int r = u + 0x7fffu + ((u >> 16) & 1u);
    return (u16)(r >> 16);
}

__device__ __forceinline__ f32x4 mfma16(bf16x8 a, bf16x8 b, f32x4 c) {
    return __builtin_amdgcn_mfma_f32_16x16x32_bf16(a, b, c, 0, 0, 0);
}

__device__ __forceinline__ void gl_lds16(const void* g, void* l) {
    __builtin_amdgcn_global_load_lds(
        (const __attribute__((address_space(1))) unsigned int*)g,
        (__attribute__((address_space(3))) unsigned int*)l, 16, 0, 0);
}

// swizzled LDS fragment read from a [rows][128B] tile
__device__ __forceinline__ bf16x8 ldsw(const u16* base, int row, int colb) {
    return *(const bf16x8*)((const char*)base + row * 128 +
                            (colb ^ ((row & 7) << 4)));
}

// --- x (fp32) -> xb (bf16) -------------------------------------------------
__global__ __launch_bounds__(256) void convx_k(const float* __restrict__ x,
                                               u16* __restrict__ xb) {
    int i = (blockIdx.x * 256 + threadIdx.x) * 8;
    const float4* p = (const float4*)(x + i);
    float4 a = p[0], c = p[1];
    u16x8 r;
    r[0] = f2bf(a.x); r[1] = f2bf(a.y); r[2] = f2bf(a.z); r[3] = f2bf(a.w);
    r[4] = f2bf(c.x); r[5] = f2bf(c.y); r[6] = f2bf(c.z); r[7] = f2bf(c.w);
    *(u16x8*)(xb + i) = r;
}

// --- W [k][n] fp32 -> Wt [z][n][k] bf16 ------------------------------------
__global__ __launch_bounds__(256) void convw_k(const float* __restrict__ wq,
                                               const float* __restrict__ wk,
                                               const float* __restrict__ wv,
                                               u16* __restrict__ wt) {
    __shared__ float tile[32][33];
    const int z = blockIdx.z;
    const float* W = (z == 0) ? wq : (z == 1) ? wk : wv;
    const int k0 = blockIdx.x * 32, n0 = blockIdx.y * 32;
    const int tx = threadIdx.x & 31, ty = threadIdx.x >> 5;
#pragma unroll
    for (int rr = 0; rr < 32; rr += 8)
        tile[ty + rr][tx] = W[(size_t)(k0 + ty + rr) * ND + n0 + tx];
    __syncthreads();
    u16* dst = wt + (size_t)z * ND * ND;
#pragma unroll
    for (int rr = 0; rr < 32; rr += 8)
        dst[(size_t)(n0 + ty + rr) * ND + k0 + tx] = f2bf(tile[tx][ty + rr]);
}

// --- z-fused QKV GEMM ------------------------------------------------------
// Grid (32,16): m0 = bx*128, n0 = by*64. 256 threads = 4 waves (2M x 2N),
// wave owns 64x32 per z. BK=64. Per K-step: stage A once (16KB) + B for
// z=0,1,2 (3x8KB), one barrier pair, 48 MFMA/wave/z-total... (3*16=48).
// A-tile L2 traffic /3 vs separate-z kernels; 3x compute per vmcnt drain.
// LDS XOR-swizzle byte^=((row&7)<<4) (inverse on global source, re-applied
// on ds_read). z<2 -> [b][h][s][64]; z==2 -> swapped mfma operands, C^T
// written as Vt [b][h][64][s].
__global__ __launch_bounds__(256) void qkv_gemm_k(const u16* __restrict__ xb,
                                                  const u16* __restrict__ wt,
                                                  u16* __restrict__ qh,
                                                  u16* __restrict__ kh,
                                                  u16* __restrict__ vt) {
    __shared__ u16 At[128 * 64];     // 16 KiB
    __shared__ u16 Bt[3][64 * 64];   // 3 x 8 KiB
    const int m0 = blockIdx.x * 128;
    const int n0 = blockIdx.y * 64;
    const int t = threadIdx.x;
    const int lane = t & 63;
    const int wv = t >> 6;
    const int wm = (wv >> 1) * 64, wn = (wv & 1) * 32;
    const int fr = lane & 15;
    const int ks = lane >> 4;

    f32x4 acc[3][4][2] = {};

    for (int kt = 0; kt < ND; kt += 64) {
        // stage A: 4 x 16B per thread, linear LDS dest, inv-swizzled source
#pragma unroll
        for (int c = 0; c < 4; c++) {
            const int L = c * 4096 + t * 16;
            const int row = L >> 7;
            const int cb = (L & 127) ^ ((row & 7) << 4);
            gl_lds16((const char*)xb + (size_t)(m0 + row) * 2048 + kt * 2 + cb,
                     (char*)At + L);
        }
        // stage B for each z: 2 x 16B per thread
#pragma unroll
        for (int z = 0; z < 3; z++)
#pragma unroll
            for (int c = 0; c < 2; c++) {
                const int L = c * 4096 + t * 16;
                const int row = L >> 7;  // 0..63
                const int cb = (L & 127) ^ ((row & 7) << 4);
                gl_lds16((const char*)wt + (size_t)z * (ND * ND * 2) +
                             (size_t)(n0 + row) * 2048 + kt * 2 + cb,
                         (char*)&Bt[z][0] + L);
            }
        __syncthreads();

        bf16x8 fa[4][2];
#pragma unroll
        for (int i = 0; i < 4; i++)
#pragma unroll
            for (int c = 0; c < 2; c++)
                fa[i][c] = ldsw(At, wm + i * 16 + fr, c * 64 + ks * 16);

#pragma unroll
        for (int z = 0; z < 3; z++) {
            bf16x8 fb[2][2];
#pragma unroll
            for (int j = 0; j < 2; j++)
#pragma unroll
                for (int c = 0; c < 2; c++)
                    fb[j][c] =
                        ldsw(&Bt[z][0], wn + j * 16 + fr, c * 64 + ks * 16);
            if (z < 2) {
#pragma unroll
                for (int i = 0; i < 4; i++)
#pragma unroll
                    for (int j = 0; j < 2; j++)
#pragma unroll
                        for (int c = 0; c < 2; c++)
                            acc[z][i][j] =
                                mfma16(fa[i][c], fb[j][c], acc[z][i][j]);
            } else {
#pragma unroll
                for (int i = 0; i < 4; i++)
#pragma unroll
                    for (int j = 0; j < 2; j++)
#pragma unroll
                        for (int c = 0; c < 2; c++)
                            acc[z][i][j] =
                                mfma16(fb[j][c], fa[i][c], acc[z][i][j]);
            }
        }
        __syncthreads();
    }

    // epilogue
#pragma unroll
    for (int z = 0; z < 2; z++) {
        u16* dst = (z == 0) ? qh : kh;
#pragma unroll
        for (int i = 0; i < 4; i++)
#pragma unroll
            for (int j = 0; j < 2; j++)
#pragma unroll
                for (int r = 0; r < 4; r++) {
                    int mg = m0 + wm + i * 16 + ks * 4 + r;
                    int ng = n0 + wn + j * 16 + fr;
                    int b = mg >> 11, s = mg & 2047;
                    int hh = ng >> 6, dd = ng & 63;
                    dst[(((size_t)b * NH + hh) * NS + s) * HD + dd] =
                        f2bf(acc[z][i][j][r]);
                }
    }
#pragma unroll
    for (int i = 0; i < 4; i++)
#pragma unroll
        for (int j = 0; j < 2; j++)
#pragma unroll
            for (int r = 0; r < 4; r++) {
                int ng = n0 + wn + j * 16 + ks * 4 + r;  // d-dim
                int mg = m0 + wm + i * 16 + fr;          // s-dim
                int b = mg >> 11, s = mg & 2047;
                int hh = ng >> 6, dd = ng & 63;
                vt[(((size_t)b * NH + hh) * HD + dd) * NS + s] =
                    f2bf(acc[2][i][j][r]);
            }
}

// --- causal flash attention ------------------------------------------------
// 512 blocks x 256 threads (4 waves). bh = blk&31 (XCD-affine), p = blk>>5.
// Block handles q-tiles A=31-p (heavy) and B=p (light): uniform 33 KV-iters.
// K/V 64-row tiles staged in LDS (double-buffered, swizzled). Chains share
// staged tiles + fragments. Fixed-reference-max softmax p=exp(s/8-8);
// row-sum via all-ones MFMA accumulator.

__device__ __forceinline__ void stage_kv(const u16* __restrict__ K,
                                         const u16* __restrict__ V, int kv0,
                                         u16* Kl, u16* Vl, int t) {
#pragma unroll
    for (int c = 0; c < 2; c++) {
        const int L = c * 4096 + t * 16;
        const int row = L >> 7;
        const int cb = (L & 127) ^ ((row & 7) << 4);
        gl_lds16((const char*)K + (size_t)(kv0 + row) * 128 + cb,
                 (char*)Kl + L);
        gl_lds16((const char*)V + (size_t)row * (NS * 2) + kv0 * 2 + cb,
                 (char*)Vl + L);
    }
}

template <bool MASKED>
__device__ __forceinline__ void sm_px(const f32x4* sc, u16* pl, int kv0,
                                      int q0, int fr, int ks) {
#pragma unroll
    for (int r = 0; r < 4; r++) {
        const int row = ks * 4 + r;
        const int qg = q0 + row;
#pragma unroll
        for (int kf = 0; kf < 4; kf++) {
            float s = sc[kf][r];
            if (MASKED && (kv0 + kf * 16 + fr > qg)) s = -3.0e38f;
            float pp = __expf(fmaf(s, 0.125f, -8.0f));
            const int k = kf * 16 + fr;
            const int c = (k >> 3) ^ (row & 7);
            *(u16*)((char*)pl + row * 128 + (c << 4) + ((k & 7) << 1)) =
                f2bf(pp);
        }
    }
}

__device__ __forceinline__ void pv_lds(const bf16x8 (*fv)[2], const u16* pl,
                                       f32x4* o, f32x4& lacc, bf16x8 ones,
                                       int fr, int ks) {
    bf16x8 pa[2];
#pragma unroll
    for (int s2 = 0; s2 < 2; s2++) {
        const int c = (s2 * 4 + ks) ^ (fr & 7);
        pa[s2] = *(const bf16x8*)((const char*)pl + fr * 128 + (c << 4));
    }
    lacc = mfma16(pa[0], ones, lacc);
    lacc = mfma16(pa[1], ones, lacc);
#pragma unroll
    for (int j = 0; j < 4; j++)
#pragma unroll
        for (int s2 = 0; s2 < 2; s2++) o[j] = mfma16(pa[s2], fv[j][s2], o[j]);
}

__global__ __launch_bounds__(256, 2) void attn_k(const u16* __restrict__ qh,
                                                 const u16* __restrict__ kh,
                                                 const u16* __restrict__ vt,
                                                 float* __restrict__ out) {
    const int t = threadIdx.x, lane = t & 63, wv = t >> 6;
    const int fr = lane & 15, ks = lane >> 4;
    const int bh = blockIdx.x & 31;
    const int p = blockIdx.x >> 5;  // 0..15
    const int b = bh >> 4, h = bh & 15;
    const int tileA = 31 - p, tileB = p;
    const int qA = tileA * 64 + wv * 16;
    const int qB = tileB * 64 + wv * 16;
    const int nA = tileA + 1, nB = tileB + 1;
    const u16* Q = qh + (size_t)bh * NS * HD;
    const u16* K = kh + (size_t)bh * NS * HD;
    const u16* V = vt + (size_t)bh * HD * NS;

    __shared__ u16 Kl[2][64 * 64];
    __shared__ u16 Vl[2][64 * 64];
    __shared__ u16 P[4][2][16 * 64];
    u16* plA = &P[wv][0][0];
    u16* plB = &P[wv][1][0];

    bf16x8 fqA[2], fqB[2];
#pragma unroll
    for (int sl = 0; sl < 2; sl++) {
        fqA[sl] = *(const bf16x8*)&Q[(qA + fr) * HD + sl * 32 + ks * 8];
        fqB[sl] = *(const bf16x8*)&Q[(qB + fr) * HD + sl * 32 + ks * 8];
    }

    u16x8 ob;
#pragma unroll
    for (int j = 0; j < 8; j++) ob[j] = 0x3F80;  // bf16 1.0
    const bf16x8 ones = __builtin_bit_cast(bf16x8, ob);

    f32x4 oA[4] = {}, oB[4] = {};
    f32x4 lA = {}, lB = {};

    stage_kv(K, V, 0, &Kl[0][0], &Vl[0][0], t);
    __syncthreads();

    for (int it = 0; it < nA; ++it) {
        const int cur = it & 1;
        const int kv0 = it * 64;
        if (it + 1 < nA)
            stage_kv(K, V, kv0 + 64, &Kl[cur ^ 1][0], &Vl[cur ^ 1][0], t);

        bf16x8 fk[4][2];
#pragma unroll
        for (int kf = 0; kf < 4; kf++)
#pragma unroll
            for (int sl = 0; sl < 2; sl++)
                fk[kf][sl] = *(const bf16x8*)((const char*)&Kl[cur][0] +
                                              (kf * 16 + fr) * 128 +
                                              ((sl * 64 + ks * 16) ^
                                               ((fr & 7) << 4)));

        f32x4 scA[4] = {};
#pragma unroll
        for (int kf = 0; kf < 4; kf++) {
            scA[kf] = mfma16(fqA[0], fk[kf][0], scA[kf]);
            scA[kf] = mfma16(fqA[1], fk[kf][1], scA[kf]);
        }
        const bool doB = it < nB;
        f32x4 scB[4] = {};
        if (doB) {
#pragma unroll
            for (int kf = 0; kf < 4; kf++) {
                scB[kf] = mfma16(fqB[0], fk[kf][0], scB[kf]);
                scB[kf] = mfma16(fqB[1], fk[kf][1], scB[kf]);
            }
        }

        if (it == nA - 1)
            sm_px<true>(scA, plA, kv0, qA, fr, ks);
        else
            sm_px<false>(scA, plA, kv0, qA, fr, ks);
        if (doB) {
            if (it == nB - 1)
                sm_px<true>(scB, plB, kv0, qB, fr, ks);
            else
                sm_px<false>(scB, plB, kv0, qB, fr, ks);
        }

        bf16x8 fv[4][2];
#pragma unroll
        for (int j = 0; j < 4; j++)
#pragma unroll
            for (int s2 = 0; s2 < 2; s2++)
                fv[j][s2] = *(const bf16x8*)((const char*)&Vl[cur][0] +
                                             (j * 16 + fr) * 128 +
                                             ((s2 * 64 + ks * 16) ^
                                              ((fr & 7) << 4)));

        pv_lds(fv, plA, oA, lA, ones, fr, ks);
        if (doB) pv_lds(fv, plB, oB, lB, ones, fr, ks);

        __syncthreads();
    }

    float rlA[4], rlB[4];
#pragma unroll
    for (int r = 0; r < 4; r++) {
        rlA[r] = 1.0f / lA[r];
        rlB[r] = 1.0f / lB[r];
    }
#pragma unroll
    for (int j = 0; j < 4; j++)
#pragma unroll
        for (int r = 0; r < 4; r++) {
            const int qgA = qA + ks * 4 + r;
            const int qgB = qB + ks * 4 + r;
            out[((size_t)b * NS + qgA) * ND + h * HD + j * 16 + fr] =
                oA[j][r] * rlA[r];
            out[((size_t)b * NS + qgB) * ND + h * HD + j * 16 + fr] =
                oB[j][r] * rlB[r];
        }
}

extern "C" void kernel_launch(void* const* d_in, const int* in_sizes, int n_in,
                              void* d_out, int out_size, void* d_ws,
                              size_t ws_size, hipStream_t stream) {
    const float* x = (const float*)d_in[0];
    const float* wq = (const float*)d_in[1];
    const float* wk = (const float*)d_in[2];
    const float* wvp = (const float*)d_in[3];
    float* out = (float*)d_out;

    char* w8 = (char*)d_ws;
    u16* xb = (u16*)(w8);                      // 8 MiB
    u16* wt = (u16*)(w8 + ((size_t)8 << 20));  // 6 MiB
    u16* qh = (u16*)(w8 + ((size_t)14 << 20));
    u16* kh = (u16*)(w8 + ((size_t)22 << 20));
    u16* vt = (u16*)(w8 + ((size_t)30 << 20));

    convx_k<<<(NB * NS * ND) / (256 * 8), 256, 0, stream>>>(x, xb);
    convw_k<<<dim3(ND / 32, ND / 32, 3), 256, 0, stream>>>(wq, wk, wvp, wt);
    qkv_gemm_k<<<dim3((NB * NS) / 128, ND / 64), 256, 0, stream>>>(
        xb, wt, qh, kh, vt);
    attn_k<<<512, 256, 0, stream>>>(qh, kh, vt, out);
}

// Round 9
// 81.368 us; speedup vs baseline: 1.7408x; 1.0186x over previous
//
#include <hip/hip_runtime.h>

// ---------------------------------------------------------------------------
// maskselfattention: B=2, S=2048, D=1024, H=16, hd=64
// convert x,W to bf16 (W transposed) -> ONE fused QKV GEMM (z-fused: A tile
// staged once, 3 B tiles, 3x MFMA per barrier; 128x64 tile, BK=64, swizzled
// LDS) writing Q,K [b][h][s][64] and V transposed [b][h][64][s] -> causal
// flash attention (4-wave blocks, paired q-tiles, LDS-staged K/V, swapped
// QK^T (S^T layout) so P stores are packed ds_write_b64, fixed-ref-max
// softmax, row-sum via all-ones MFMA).
// ---------------------------------------------------------------------------

typedef unsigned short u16;
typedef unsigned int u32;
typedef unsigned long long u64;
typedef __bf16 bf16x8 __attribute__((ext_vector_type(8)));
typedef float f32x4 __attribute__((ext_vector_type(4)));
typedef u16 u16x8 __attribute__((ext_vector_type(8)));

#define NB 2
#define NS 2048
#define ND 1024
#define NH 16
#define HD 64

__device__ __forceinline__ u16 f2bf(float f) {
    unsigned int u = __float_as_uint(f);
    unsigned int r = u + 0x7fffu + ((u >> 16) & 1u);
    return (u16)(r >> 16);
}

__device__ __forceinline__ f32x4 mfma16(bf16x8 a, bf16x8 b, f32x4 c) {
    return __builtin_amdgcn_mfma_f32_16x16x32_bf16(a, b, c, 0, 0, 0);
}

__device__ __forceinline__ void gl_lds16(const void* g, void* l) {
    __builtin_amdgcn_global_load_lds(
        (const __attribute__((address_space(1))) unsigned int*)g,
        (__attribute__((address_space(3))) unsigned int*)l, 16, 0, 0);
}

// swizzled LDS fragment read from a [rows][128B] tile
__device__ __forceinline__ bf16x8 ldsw(const u16* base, int row, int colb) {
    return *(const bf16x8*)((const char*)base + row * 128 +
                            (colb ^ ((row & 7) << 4)));
}

// --- x (fp32) -> xb (bf16) -------------------------------------------------
__global__ __launch_bounds__(256) void convx_k(const float* __restrict__ x,
                                               u16* __restrict__ xb) {
    int i = (blockIdx.x * 256 + threadIdx.x) * 8;
    const float4* p = (const float4*)(x + i);
    float4 a = p[0], c = p[1];
    u16x8 r;
    r[0] = f2bf(a.x); r[1] = f2bf(a.y); r[2] = f2bf(a.z); r[3] = f2bf(a.w);
    r[4] = f2bf(c.x); r[5] = f2bf(c.y); r[6] = f2bf(c.z); r[7] = f2bf(c.w);
    *(u16x8*)(xb + i) = r;
}

// --- W [k][n] fp32 -> Wt [z][n][k] bf16 ------------------------------------
__global__ __launch_bounds__(256) void convw_k(const float* __restrict__ wq,
                                               const float* __restrict__ wk,
                                               const float* __restrict__ wv,
                                               u16* __restrict__ wt) {
    __shared__ float tile[32][33];
    const int z = blockIdx.z;
    const float* W = (z == 0) ? wq : (z == 1) ? wk : wv;
    const int k0 = blockIdx.x * 32, n0 = blockIdx.y * 32;
    const int tx = threadIdx.x & 31, ty = threadIdx.x >> 5;
#pragma unroll
    for (int rr = 0; rr < 32; rr += 8)
        tile[ty + rr][tx] = W[(size_t)(k0 + ty + rr) * ND + n0 + tx];
    __syncthreads();
    u16* dst = wt + (size_t)z * ND * ND;
#pragma unroll
    for (int rr = 0; rr < 32; rr += 8)
        dst[(size_t)(n0 + ty + rr) * ND + k0 + tx] = f2bf(tile[tx][ty + rr]);
}

// --- z-fused QKV GEMM ------------------------------------------------------
// Grid (32,16): m0 = bx*128, n0 = by*64. 256 threads = 4 waves (2M x 2N),
// wave owns 64x32 per z. BK=64. A staged once + 3 B tiles per K-step.
__global__ __launch_bounds__(256) void qkv_gemm_k(const u16* __restrict__ xb,
                                                  const u16* __restrict__ wt,
                                                  u16* __restrict__ qh,
                                                  u16* __restrict__ kh,
                                                  u16* __restrict__ vt) {
    __shared__ u16 At[128 * 64];     // 16 KiB
    __shared__ u16 Bt[3][64 * 64];   // 3 x 8 KiB
    const int m0 = blockIdx.x * 128;
    const int n0 = blockIdx.y * 64;
    const int t = threadIdx.x;
    const int lane = t & 63;
    const int wv = t >> 6;
    const int wm = (wv >> 1) * 64, wn = (wv & 1) * 32;
    const int fr = lane & 15;
    const int ks = lane >> 4;

    f32x4 acc[3][4][2] = {};

    for (int kt = 0; kt < ND; kt += 64) {
#pragma unroll
        for (int c = 0; c < 4; c++) {
            const int L = c * 4096 + t * 16;
            const int row = L >> 7;
            const int cb = (L & 127) ^ ((row & 7) << 4);
            gl_lds16((const char*)xb + (size_t)(m0 + row) * 2048 + kt * 2 + cb,
                     (char*)At + L);
        }
#pragma unroll
        for (int z = 0; z < 3; z++)
#pragma unroll
            for (int c = 0; c < 2; c++) {
                const int L = c * 4096 + t * 16;
                const int row = L >> 7;  // 0..63
                const int cb = (L & 127) ^ ((row & 7) << 4);
                gl_lds16((const char*)wt + (size_t)z * (ND * ND * 2) +
                             (size_t)(n0 + row) * 2048 + kt * 2 + cb,
                         (char*)&Bt[z][0] + L);
            }
        __syncthreads();

        bf16x8 fa[4][2];
#pragma unroll
        for (int i = 0; i < 4; i++)
#pragma unroll
            for (int c = 0; c < 2; c++)
                fa[i][c] = ldsw(At, wm + i * 16 + fr, c * 64 + ks * 16);

#pragma unroll
        for (int z = 0; z < 3; z++) {
            bf16x8 fb[2][2];
#pragma unroll
            for (int j = 0; j < 2; j++)
#pragma unroll
                for (int c = 0; c < 2; c++)
                    fb[j][c] =
                        ldsw(&Bt[z][0], wn + j * 16 + fr, c * 64 + ks * 16);
            if (z < 2) {
#pragma unroll
                for (int i = 0; i < 4; i++)
#pragma unroll
                    for (int j = 0; j < 2; j++)
#pragma unroll
                        for (int c = 0; c < 2; c++)
                            acc[z][i][j] =
                                mfma16(fa[i][c], fb[j][c], acc[z][i][j]);
            } else {
#pragma unroll
                for (int i = 0; i < 4; i++)
#pragma unroll
                    for (int j = 0; j < 2; j++)
#pragma unroll
                        for (int c = 0; c < 2; c++)
                            acc[z][i][j] =
                                mfma16(fb[j][c], fa[i][c], acc[z][i][j]);
            }
        }
        __syncthreads();
    }

#pragma unroll
    for (int z = 0; z < 2; z++) {
        u16* dst = (z == 0) ? qh : kh;
#pragma unroll
        for (int i = 0; i < 4; i++)
#pragma unroll
            for (int j = 0; j < 2; j++)
#pragma unroll
                for (int r = 0; r < 4; r++) {
                    int mg = m0 + wm + i * 16 + ks * 4 + r;
                    int ng = n0 + wn + j * 16 + fr;
                    int b = mg >> 11, s = mg & 2047;
                    int hh = ng >> 6, dd = ng & 63;
                    dst[(((size_t)b * NH + hh) * NS + s) * HD + dd] =
                        f2bf(acc[z][i][j][r]);
                }
    }
#pragma unroll
    for (int i = 0; i < 4; i++)
#pragma unroll
        for (int j = 0; j < 2; j++)
#pragma unroll
            for (int r = 0; r < 4; r++) {
                int ng = n0 + wn + j * 16 + ks * 4 + r;  // d-dim
                int mg = m0 + wm + i * 16 + fr;          // s-dim
                int b = mg >> 11, s = mg & 2047;
                int hh = ng >> 6, dd = ng & 63;
                vt[(((size_t)b * NH + hh) * HD + dd) * NS + s] =
                    f2bf(acc[2][i][j][r]);
            }
}

// --- causal flash attention ------------------------------------------------
// 512 blocks x 256 threads (4 waves). bh = blk&31 (XCD-affine), p = blk>>5.
// Block handles q-tiles A=31-p (heavy) and B=p (light): uniform 33 KV-iters.
// K/V 64-row tiles staged in LDS (double-buffered, swizzled).
// QK^T computed SWAPPED: sc = mfma(K,Q) -> sc[kf][r] = S[kv0+16kf+4ks+r]
// [q0+fr] -- kv runs of 4 are register-consecutive, so the P-store is 4
// packed ds_write_b64 per chain (vs 16 scalar b16): ~3x fewer DS write
// cycles (DS pipe was the measured bottleneck, r8).
// Fixed-reference-max softmax p=exp(s/8-8); row-sum via all-ones MFMA.

__device__ __forceinline__ void stage_kv(const u16* __restrict__ K,
                                         const u16* __restrict__ V, int kv0,
                                         u16* Kl, u16* Vl, int t) {
#pragma unroll
    for (int c = 0; c < 2; c++) {
        const int L = c * 4096 + t * 16;
        const int row = L >> 7;
        const int cb = (L & 127) ^ ((row & 7) << 4);
        gl_lds16((const char*)K + (size_t)(kv0 + row) * 128 + cb,
                 (char*)Kl + L);
        gl_lds16((const char*)V + (size_t)row * (NS * 2) + kv0 * 2 + cb,
                 (char*)Vl + L);
    }
}

// sc holds S^T fragments; write P[q=fr][kv] as 4 x ds_write_b64
template <bool MASKED>
__device__ __forceinline__ void sm_pxT(const f32x4* sc, u16* pl, int kv0,
                                       int q0, int fr, int ks) {
    const int qg = q0 + fr;
#pragma unroll
    for (int kf = 0; kf < 4; kf++) {
        const int kvb = kv0 + kf * 16 + ks * 4;
        float p[4];
#pragma unroll
        for (int r = 0; r < 4; r++) {
            float s = sc[kf][r];
            if (MASKED && (kvb + r > qg)) s = -3.0e38f;
            p[r] = __expf(fmaf(s, 0.125f, -8.0f));
        }
        u64 w = (u64)f2bf(p[0]) | ((u64)f2bf(p[1]) << 16) |
                ((u64)f2bf(p[2]) << 32) | ((u64)f2bf(p[3]) << 48);
        const int chunk = (2 * kf + (ks >> 1)) ^ (fr & 7);
        *(u64*)((char*)pl + fr * 128 + (chunk << 4) + ((ks & 1) << 3)) = w;
    }
}

__device__ __forceinline__ void pv_lds(const bf16x8 (*fv)[2], const u16* pl,
                                       f32x4* o, f32x4& lacc, bf16x8 ones,
                                       int fr, int ks) {
    bf16x8 pa[2];
#pragma unroll
    for (int s2 = 0; s2 < 2; s2++) {
        const int c = (s2 * 4 + ks) ^ (fr & 7);
        pa[s2] = *(const bf16x8*)((const char*)pl + fr * 128 + (c << 4));
    }
    lacc = mfma16(pa[0], ones, lacc);
    lacc = mfma16(pa[1], ones, lacc);
#pragma unroll
    for (int j = 0; j < 4; j++)
#pragma unroll
        for (int s2 = 0; s2 < 2; s2++) o[j] = mfma16(pa[s2], fv[j][s2], o[j]);
}

__global__ __launch_bounds__(256, 2) void attn_k(const u16* __restrict__ qh,
                                                 const u16* __restrict__ kh,
                                                 const u16* __restrict__ vt,
                                                 float* __restrict__ out) {
    const int t = threadIdx.x, lane = t & 63, wv = t >> 6;
    const int fr = lane & 15, ks = lane >> 4;
    const int bh = blockIdx.x & 31;
    const int p = blockIdx.x >> 5;  // 0..15
    const int b = bh >> 4, h = bh & 15;
    const int tileA = 31 - p, tileB = p;
    const int qA = tileA * 64 + wv * 16;
    const int qB = tileB * 64 + wv * 16;
    const int nA = tileA + 1, nB = tileB + 1;
    const u16* Q = qh + (size_t)bh * NS * HD;
    const u16* K = kh + (size_t)bh * NS * HD;
    const u16* V = vt + (size_t)bh * HD * NS;

    __shared__ u16 Kl[2][64 * 64];
    __shared__ u16 Vl[2][64 * 64];
    __shared__ u16 P[4][2][16 * 64];
    u16* plA = &P[wv][0][0];
    u16* plB = &P[wv][1][0];

    bf16x8 fqA[2], fqB[2];
#pragma unroll
    for (int sl = 0; sl < 2; sl++) {
        fqA[sl] = *(const bf16x8*)&Q[(qA + fr) * HD + sl * 32 + ks * 8];
        fqB[sl] = *(const bf16x8*)&Q[(qB + fr) * HD + sl * 32 + ks * 8];
    }

    u16x8 ob;
#pragma unroll
    for (int j = 0; j < 8; j++) ob[j] = 0x3F80;  // bf16 1.0
    const bf16x8 ones = __builtin_bit_cast(bf16x8, ob);

    f32x4 oA[4] = {}, oB[4] = {};
    f32x4 lA = {}, lB = {};

    stage_kv(K, V, 0, &Kl[0][0], &Vl[0][0], t);
    __syncthreads();

    for (int it = 0; it < nA; ++it) {
        const int cur = it & 1;
        const int kv0 = it * 64;
        if (it + 1 < nA)
            stage_kv(K, V, kv0 + 64, &Kl[cur ^ 1][0], &Vl[cur ^ 1][0], t);

        bf16x8 fk[4][2];
#pragma unroll
        for (int kf = 0; kf < 4; kf++)
#pragma unroll
            for (int sl = 0; sl < 2; sl++)
                fk[kf][sl] = *(const bf16x8*)((const char*)&Kl[cur][0] +
                                              (kf * 16 + fr) * 128 +
                                              ((sl * 64 + ks * 16) ^
                                               ((fr & 7) << 4)));

        // swapped QK^T: sc = S^T fragments
        f32x4 scA[4] = {};
#pragma unroll
        for (int kf = 0; kf < 4; kf++) {
            scA[kf] = mfma16(fk[kf][0], fqA[0], scA[kf]);
            scA[kf] = mfma16(fk[kf][1], fqA[1], scA[kf]);
        }
        const bool doB = it < nB;
        f32x4 scB[4] = {};
        if (doB) {
#pragma unroll
            for (int kf = 0; kf < 4; kf++) {
                scB[kf] = mfma16(fk[kf][0], fqB[0], scB[kf]);
                scB[kf] = mfma16(fk[kf][1], fqB[1], scB[kf]);
            }
        }

        if (it == nA - 1)
            sm_pxT<true>(scA, plA, kv0, qA, fr, ks);
        else
            sm_pxT<false>(scA, plA, kv0, qA, fr, ks);
        if (doB) {
            if (it == nB - 1)
                sm_pxT<true>(scB, plB, kv0, qB, fr, ks);
            else
                sm_pxT<false>(scB, plB, kv0, qB, fr, ks);
        }

        bf16x8 fv[4][2];
#pragma unroll
        for (int j = 0; j < 4; j++)
#pragma unroll
            for (int s2 = 0; s2 < 2; s2++)
                fv[j][s2] = *(const bf16x8*)((const char*)&Vl[cur][0] +
                                             (j * 16 + fr) * 128 +
                                             ((s2 * 64 + ks * 16) ^
                                              ((fr & 7) << 4)));

        pv_lds(fv, plA, oA, lA, ones, fr, ks);
        if (doB) pv_lds(fv, plB, oB, lB, ones, fr, ks);

        __syncthreads();
    }

    float rlA[4], rlB[4];
#pragma unroll
    for (int r = 0; r < 4; r++) {
        rlA[r] = 1.0f / lA[r];
        rlB[r] = 1.0f / lB[r];
    }
#pragma unroll
    for (int j = 0; j < 4; j++)
#pragma unroll
        for (int r = 0; r < 4; r++) {
            const int qgA = qA + ks * 4 + r;
            const int qgB = qB + ks * 4 + r;
            out[((size_t)b * NS + qgA) * ND + h * HD + j * 16 + fr] =
                oA[j][r] * rlA[r];
            out[((size_t)b * NS + qgB) * ND + h * HD + j * 16 + fr] =
                oB[j][r] * rlB[r];
        }
}

extern "C" void kernel_launch(void* const* d_in, const int* in_sizes, int n_in,
                              void* d_out, int out_size, void* d_ws,
                              size_t ws_size, hipStream_t stream) {
    const float* x = (const float*)d_in[0];
    const float* wq = (const float*)d_in[1];
    const float* wk = (const float*)d_in[2];
    const float* wvp = (const float*)d_in[3];
    float* out = (float*)d_out;

    char* w8 = (char*)d_ws;
    u16* xb = (u16*)(w8);                      // 8 MiB
    u16* wt = (u16*)(w8 + ((size_t)8 << 20));  // 6 MiB
    u16* qh = (u16*)(w8 + ((size_t)14 << 20));
    u16* kh = (u16*)(w8 + ((size_t)22 << 20));
    u16* vt = (u16*)(w8 + ((size_t)30 << 20));

    convx_k<<<(NB * NS * ND) / (256 * 8), 256, 0, stream>>>(x, xb);
    convw_k<<<dim3(ND / 32, ND / 32, 3), 256, 0, stream>>>(wq, wk, wvp, wt);
    qkv_gemm_k<<<dim3((NB * NS) / 128, ND / 64), 256, 0, stream>>>(
        xb, wt, qh, kh, vt);
    attn_k<<<512, 256, 0, stream>>>(qh, kh, vt, out);
}